// Round 9
// baseline (169.533 us; speedup 1.0000x reference)
//
#include <hip/hip_runtime.h>
#include <stdint.h>

#define NB 64
#define NC 512
#define NPTS 3000
#define MAXH 70
#define MAXW 40
#define HW (MAXH * MAXW)   // 2800
#define THREADS 256
#define CPB 32             // channels per block
#define NV4 750            // float4 per feature row (3000 floats)
#define NV4P 768           // padded buffer (float4) -> 12288 B
#define OV4 (HW / 4)       // 700 float4 per output row
#define FIXCAP 8192
// ws layout: [0..16) fix_cnt | [16..16+FIXCAP*4) fix_list | inv maps (64*2800 int)
#define WS_INV_OFF (16 + FIXCAP * 4)                 // 32784, 16B-aligned
#define WS_NEED    (WS_INV_OFF + NB * HW * 4)        // 749584 B

typedef float f32x4 __attribute__((ext_vector_type(4)));  // native vec for NT store

// async global -> LDS DMA, 16 B per lane (HW: wave-uniform base + lane*16)
__device__ __forceinline__ void gload_lds16(const void* g, void* l) {
    __builtin_amdgcn_global_load_lds(
        (const __attribute__((address_space(1))) uint32_t*)g,
        (__attribute__((address_space(3))) uint32_t*)l,
        16, 0, 0);
}

// reset the fixup counter (ws is NOT re-poisoned between replays)
__global__ void fm_zero_cnt(int* cnt) {
    if (threadIdx.x == 0) cnt[0] = 0;
}

// ============================================================================
// Kernel A: one block per batch item -- compute crop params + inverse map,
// write inv[b][HW] to workspace. Runs once; removes the 16x-redundant
// preamble from the gather kernel.
// ============================================================================
__launch_bounds__(THREADS)
__global__ void fm_inv_kernel(const int* __restrict__ ys,
                              const int* __restrict__ xs,
                              int* __restrict__ invg)
{
    __shared__ int inv[HW];        // 11.2 KB
    __shared__ int ybuf[NPTS];     // 12 KB
    __shared__ int xbuf[NPTS];     // 12 KB
    __shared__ int s_red[16];
    __shared__ int s_par[5];

    const int b   = blockIdx.x;
    const int tid = threadIdx.x;
    const int lane = tid & 63;
    const int w    = tid >> 6;

    const int* ysb = ys + b * NPTS;
    const int* xsb = xs + b * NPTS;

    int vminY = 0x7fffffff, vminX = 0x7fffffff;
    int vmaxY = -0x7fffffff, vmaxX = -0x7fffffff;
    for (int i = tid; i < NV4; i += THREADS) {
        int4 ya = ((const int4*)ysb)[i];
        int4 xa = ((const int4*)xsb)[i];
        ((int4*)ybuf)[i] = ya;
        ((int4*)xbuf)[i] = xa;
        int yv[4] = {ya.x, ya.y, ya.z, ya.w};
        int xv[4] = {xa.x, xa.y, xa.z, xa.w};
#pragma unroll
        for (int j = 0; j < 4; ++j) {
            if (yv[j] > -1) {
                vminY = min(vminY, yv[j]); vmaxY = max(vmaxY, yv[j]);
                vminX = min(vminX, xv[j]); vmaxX = max(vmaxX, xv[j]);
            }
        }
    }
    for (int i = tid; i < HW; i += THREADS) inv[i] = -1;
#pragma unroll
    for (int off = 32; off > 0; off >>= 1) {
        vminY = min(vminY, __shfl_xor(vminY, off));
        vmaxY = max(vmaxY, __shfl_xor(vmaxY, off));
        vminX = min(vminX, __shfl_xor(vminX, off));
        vmaxX = max(vmaxX, __shfl_xor(vmaxX, off));
    }
    if (lane == 0) {
        s_red[w]      = vminY;
        s_red[4  + w] = vmaxY;
        s_red[8  + w] = vminX;
        s_red[12 + w] = vmaxX;
    }
    __syncthreads();
    if (tid == 0) {
        int mnY = min(min(s_red[0], s_red[1]),   min(s_red[2],  s_red[3]));
        int mxY = max(max(s_red[4], s_red[5]),   max(s_red[6],  s_red[7]));
        int mnX = min(min(s_red[8], s_red[9]),   min(s_red[10], s_red[11]));
        int mxX = max(max(s_red[12], s_red[13]), max(s_red[14], s_red[15]));
        int h  = mxY - mnY + 1;
        int w_ = mxX - mnX + 1;
        int swap = (w_ > h) ? 1 : 0;
        int H0 = swap ? w_ : h;
        int W0 = swap ? h : w_;
        int h_dif = H0 - MAXH;
        int w_dif = W0 - MAXW;
        int cut_top  = (h_dif > 0) ? (h_dif + 1) / 2 : 0;
        int pad_top  = (h_dif > 0) ? 0 : (-h_dif + 1) / 2;
        int cut_left = (w_dif > 0) ? (w_dif + 1) / 2 : 0;
        int left_pad = (w_dif > 0) ? 0 : (-w_dif + 1) / 2;  // ref pads "right" on the LEFT
        s_par[0] = swap;
        s_par[1] = mnY;
        s_par[2] = mnX;
        s_par[3] = pad_top - cut_top;
        s_par[4] = left_pad - cut_left;
    }
    __syncthreads();
    {
        const int swp = s_par[0], mnY = s_par[1], mnX = s_par[2];
        const int roff = s_par[3], coff = s_par[4];
        for (int n = tid; n < NPTS; n += THREADS) {
            int y = ybuf[n];
            int x = xbuf[n];
            if (y > -1) {
                int r  = swp ? (x - mnX) : (y - mnY);
                int cl = swp ? (y - mnY) : (x - mnX);
                int rr = r + roff;
                int cc = cl + coff;
                if (rr >= 0 && rr < MAXH && cc >= 0 && cc < MAXW)
                    inv[rr * MAXW + cc] = n;   // unique targets per setup
            }
        }
    }
    __syncthreads();
    // coalesced copy out: 700 int4
    int4* dst = (int4*)(invg + b * HW);
    for (int i = tid; i < OV4; i += THREADS) dst[i] = ((const int4*)inv)[i];
}

// ============================================================================
// Kernel B: gather/scatter with precomputed inv map. Triple-buffered LDS
// channel pipeline, 1 raw barrier + counted vmcnt per channel (R6 schedule).
// Preamble = 3 int4 loads; no block-wide preamble syncs.
// ============================================================================
__launch_bounds__(THREADS)
__global__ void fm_gather_pre_kernel(const float* __restrict__ feat,
                                     const int* __restrict__ invg,
                                     float* __restrict__ out,
                                     int* __restrict__ fix_cnt,
                                     int* __restrict__ fix_list,
                                     int fix_cap)
{
    __shared__ float4 tb[3][NV4P];          // 36.9 KB

    const int blocks_per_b = NC / CPB;      // 16
    const int b   = blockIdx.x / blocks_per_b;
    const int c0  = (blockIdx.x % blocks_per_b) * CPB;
    const int tid = threadIdx.x;

    // nreg: this thread's 12 inv entries (channel-invariant), 3 coalesced int4
    // loads from the precomputed map (L2-resident: 16 blocks share a row).
    int nreg[3][4];
    {
        const int4* src = (const int4*)(invg + b * HW);
#pragma unroll
        for (int it = 0; it < 3; ++it) {
            int i4 = it * THREADS + tid;
            if (i4 < OV4) {
                int4 t = src[i4];
                nreg[it][0] = t.x; nreg[it][1] = t.y;
                nreg[it][2] = t.z; nreg[it][3] = t.w;
            }
        }
    }

    // prologue: DMA ch0 into tb[0] (3 issues/thread-row; tail lanes clamp src)
    {
        const float4* src = (const float4*)(feat + (size_t)(b * NC + c0) * NPTS);
#pragma unroll
        for (int it = 0; it < 3; ++it) {
            int i = it * THREADS + tid;
            int s = (i < NV4) ? i : (NV4 - 1);
            gload_lds16(src + s, tb[0] + i);
        }
    }

    // Triple-buffered pipeline. Per iter per wave: 3 gload_lds (ch ci+1),
    // then <=3 NT stores (ch ci). vmcnt analysis:
    //  - iter 0: outstanding = {3 nreg int4 (oldest-ish), 3 DMA ch0, 3 DMA ch1}.
    //    ch0's DMAs are always within the oldest 6 (intrinsics keep program
    //    order; plain loads may sink but that only helps) -> vmcnt(3) retires
    //    everything but the 3 newest => ch0 + nreg done.
    //  - steady: newer-than-loads-ci = stores(ci-1) <=3 + loads(ci+1) 3 ->
    //    vmcnt(5) (tail wave has 2 stores; 5 is safe-conservative).
    //  - last iter: no prefetch -> vmcnt(2).
    int cur = 0;
    for (int ci = 0; ci < CPB; ++ci) {
        const int nxt = (cur == 2) ? 0 : cur + 1;
        if (ci + 1 < CPB) {
            const float4* src =
                (const float4*)(feat + (size_t)(b * NC + c0 + ci + 1) * NPTS);
            float4* bn = tb[nxt];
#pragma unroll
            for (int it = 0; it < 3; ++it) {
                int i = it * THREADS + tid;
                int s = (i < NV4) ? i : (NV4 - 1);
                gload_lds16(src + s, bn + i);
            }
        }
        if (ci == 0) {
            asm volatile("s_waitcnt vmcnt(3)" ::: "memory");
        } else if (ci + 1 < CPB) {
            asm volatile("s_waitcnt vmcnt(5)" ::: "memory");
        } else {
            asm volatile("s_waitcnt vmcnt(2)" ::: "memory");
        }
        __builtin_amdgcn_sched_barrier(0);
        __builtin_amdgcn_s_barrier();      // all waves' loads-ci landed
        __builtin_amdgcn_sched_barrier(0);

        const float* fp = (const float*)tb[cur];
        f32x4* orow = (f32x4*)(out + (size_t)(b * NC + c0 + ci) * HW);
#pragma unroll
        for (int it = 0; it < 3; ++it) {
            int i4 = it * THREADS + tid;
            if (i4 < OV4) {
                f32x4 v;
#pragma unroll
                for (int j = 0; j < 4; ++j) {
                    int n = nreg[it][j];
                    float val = 0.0f;
                    if (n >= 0) {
                        val = fp[n];
                        if (val == -1.0f) {
                            // scattered cell containing exact -1.0 -> zero whole cell
                            int pos = atomicAdd(fix_cnt, 1);
                            if (pos < fix_cap) fix_list[pos] = b * HW + i4 * 4 + j;
                        }
                    }
                    v[j] = val;
                }
                __builtin_nontemporal_store(v, &orow[i4]);
            }
        }
        cur = nxt;
    }
}

// ============================================================================
// Monolithic fallback (R8 kernel, used only if ws is too small for inv maps)
// ============================================================================
__launch_bounds__(THREADS)
__global__ void fm_gather_mono_kernel(const float* __restrict__ feat,
                                      const int* __restrict__ ys,
                                      const int* __restrict__ xs,
                                      float* __restrict__ out,
                                      int* __restrict__ fix_cnt,
                                      int* __restrict__ fix_list,
                                      int fix_cap)
{
    __shared__ float4 tb[3][NV4P];
    __shared__ int    s_red[16];
    __shared__ int    s_par[5];

    const int blocks_per_b = NC / CPB;
    const int b   = blockIdx.x / blocks_per_b;
    const int c0  = (blockIdx.x % blocks_per_b) * CPB;
    const int tid = threadIdx.x;
    const int lane = tid & 63;
    const int w    = tid >> 6;

    const int* ysb = ys + b * NPTS;
    const int* xsb = xs + b * NPTS;
    int* ybuf = (int*)tb[0];
    int* xbuf = (int*)tb[1];
    int* inv  = (int*)tb[2];

    int vminY = 0x7fffffff, vminX = 0x7fffffff;
    int vmaxY = -0x7fffffff, vmaxX = -0x7fffffff;
    for (int i = tid; i < NV4; i += THREADS) {
        int4 ya = ((const int4*)ysb)[i];
        int4 xa = ((const int4*)xsb)[i];
        ((int4*)ybuf)[i] = ya;
        ((int4*)xbuf)[i] = xa;
        int yv[4] = {ya.x, ya.y, ya.z, ya.w};
        int xv[4] = {xa.x, xa.y, xa.z, xa.w};
#pragma unroll
        for (int j = 0; j < 4; ++j) {
            if (yv[j] > -1) {
                vminY = min(vminY, yv[j]); vmaxY = max(vmaxY, yv[j]);
                vminX = min(vminX, xv[j]); vmaxX = max(vmaxX, xv[j]);
            }
        }
    }
    for (int i = tid; i < HW; i += THREADS) inv[i] = -1;
#pragma unroll
    for (int off = 32; off > 0; off >>= 1) {
        vminY = min(vminY, __shfl_xor(vminY, off));
        vmaxY = max(vmaxY, __shfl_xor(vmaxY, off));
        vminX = min(vminX, __shfl_xor(vminX, off));
        vmaxX = max(vmaxX, __shfl_xor(vmaxX, off));
    }
    if (lane == 0) {
        s_red[w]      = vminY;
        s_red[4  + w] = vmaxY;
        s_red[8  + w] = vminX;
        s_red[12 + w] = vmaxX;
    }
    __syncthreads();
    if (tid == 0) {
        int mnY = min(min(s_red[0], s_red[1]),   min(s_red[2],  s_red[3]));
        int mxY = max(max(s_red[4], s_red[5]),   max(s_red[6],  s_red[7]));
        int mnX = min(min(s_red[8], s_red[9]),   min(s_red[10], s_red[11]));
        int mxX = max(max(s_red[12], s_red[13]), max(s_red[14], s_red[15]));
        int h  = mxY - mnY + 1;
        int w_ = mxX - mnX + 1;
        int swap = (w_ > h) ? 1 : 0;
        int H0 = swap ? w_ : h;
        int W0 = swap ? h : w_;
        int h_dif = H0 - MAXH;
        int w_dif = W0 - MAXW;
        int cut_top  = (h_dif > 0) ? (h_dif + 1) / 2 : 0;
        int pad_top  = (h_dif > 0) ? 0 : (-h_dif + 1) / 2;
        int cut_left = (w_dif > 0) ? (w_dif + 1) / 2 : 0;
        int left_pad = (w_dif > 0) ? 0 : (-w_dif + 1) / 2;
        s_par[0] = swap;
        s_par[1] = mnY;
        s_par[2] = mnX;
        s_par[3] = pad_top - cut_top;
        s_par[4] = left_pad - cut_left;
    }
    __syncthreads();
    {
        const int swp = s_par[0], mnY = s_par[1], mnX = s_par[2];
        const int roff = s_par[3], coff = s_par[4];
        for (int n = tid; n < NPTS; n += THREADS) {
            int y = ybuf[n];
            int x = xbuf[n];
            if (y > -1) {
                int r  = swp ? (x - mnX) : (y - mnY);
                int cl = swp ? (y - mnY) : (x - mnX);
                int rr = r + roff;
                int cc = cl + coff;
                if (rr >= 0 && rr < MAXH && cc >= 0 && cc < MAXW)
                    inv[rr * MAXW + cc] = n;
            }
        }
    }
    __syncthreads();

    int nreg[3][4];
#pragma unroll
    for (int it = 0; it < 3; ++it) {
        int i4 = it * THREADS + tid;
        if (i4 < OV4) {
#pragma unroll
            for (int j = 0; j < 4; ++j) nreg[it][j] = inv[i4 * 4 + j];
        }
    }
    __syncthreads();

    {
        const float4* src = (const float4*)(feat + (size_t)(b * NC + c0) * NPTS);
#pragma unroll
        for (int it = 0; it < 3; ++it) {
            int i = it * THREADS + tid;
            int s = (i < NV4) ? i : (NV4 - 1);
            gload_lds16(src + s, tb[0] + i);
        }
    }

    int cur = 0;
    for (int ci = 0; ci < CPB; ++ci) {
        const int nxt = (cur == 2) ? 0 : cur + 1;
        if (ci + 1 < CPB) {
            const float4* src =
                (const float4*)(feat + (size_t)(b * NC + c0 + ci + 1) * NPTS);
            float4* bn = tb[nxt];
#pragma unroll
            for (int it = 0; it < 3; ++it) {
                int i = it * THREADS + tid;
                int s = (i < NV4) ? i : (NV4 - 1);
                gload_lds16(src + s, bn + i);
            }
        }
        if (ci == 0) {
            asm volatile("s_waitcnt vmcnt(3)" ::: "memory");
        } else if (ci + 1 < CPB) {
            asm volatile("s_waitcnt vmcnt(5)" ::: "memory");
        } else {
            asm volatile("s_waitcnt vmcnt(2)" ::: "memory");
        }
        __builtin_amdgcn_sched_barrier(0);
        __builtin_amdgcn_s_barrier();
        __builtin_amdgcn_sched_barrier(0);

        const float* fp = (const float*)tb[cur];
        f32x4* orow = (f32x4*)(out + (size_t)(b * NC + c0 + ci) * HW);
#pragma unroll
        for (int it = 0; it < 3; ++it) {
            int i4 = it * THREADS + tid;
            if (i4 < OV4) {
                f32x4 v;
#pragma unroll
                for (int j = 0; j < 4; ++j) {
                    int n = nreg[it][j];
                    float val = 0.0f;
                    if (n >= 0) {
                        val = fp[n];
                        if (val == -1.0f) {
                            int pos = atomicAdd(fix_cnt, 1);
                            if (pos < fix_cap) fix_list[pos] = b * HW + i4 * 4 + j;
                        }
                    }
                    v[j] = val;
                }
                __builtin_nontemporal_store(v, &orow[i4]);
            }
        }
        cur = nxt;
    }
}

__global__ void fm_fixup_kernel(const int* __restrict__ fix_cnt,
                                const int* __restrict__ fix_list,
                                int fix_cap,
                                float* __restrict__ out)
{
    int count = min(fix_cnt[0], fix_cap);
    long total = (long)count * NC;
    long stride = (long)gridDim.x * blockDim.x;
    for (long t = (long)blockIdx.x * blockDim.x + threadIdx.x; t < total; t += stride) {
        int e = (int)(t / NC);
        int c = (int)(t % NC);
        int cell = fix_list[e];
        int b   = cell / HW;
        int pos = cell % HW;
        __builtin_nontemporal_store(0.0f, &out[(size_t)(b * NC + c) * HW + pos]);
    }
}

extern "C" void kernel_launch(void* const* d_in, const int* in_sizes, int n_in,
                              void* d_out, int out_size, void* d_ws, size_t ws_size,
                              hipStream_t stream) {
    const float* feat = (const float*)d_in[0];
    const int*   ys   = (const int*)d_in[1];
    const int*   xs   = (const int*)d_in[2];
    float* out = (float*)d_out;

    int* fix_cnt  = (int*)d_ws;
    int* fix_list = (int*)((char*)d_ws + 16);

    fm_zero_cnt<<<1, 64, 0, stream>>>(fix_cnt);

    const int grid = NB * (NC / CPB);  // 1024 blocks = 4 per CU

    if (ws_size >= (size_t)WS_NEED) {
        int* invg = (int*)((char*)d_ws + WS_INV_OFF);
        fm_inv_kernel<<<NB, THREADS, 0, stream>>>(ys, xs, invg);
        fm_gather_pre_kernel<<<grid, THREADS, 0, stream>>>(feat, invg, out,
                                                           fix_cnt, fix_list,
                                                           FIXCAP);
        fm_fixup_kernel<<<128, 256, 0, stream>>>(fix_cnt, fix_list, FIXCAP, out);
    } else {
        int fix_cap = 0;
        if (ws_size > 16) {
            size_t avail = (ws_size - 16) / 4;
            fix_cap = (int)((avail < FIXCAP) ? avail : FIXCAP);
        }
        fm_gather_mono_kernel<<<grid, THREADS, 0, stream>>>(feat, ys, xs, out,
                                                            fix_cnt, fix_list,
                                                            fix_cap);
        fm_fixup_kernel<<<128, 256, 0, stream>>>(fix_cnt, fix_list, fix_cap, out);
    }
}

// Round 10
// 168.111 us; speedup vs baseline: 1.0085x; 1.0085x over previous
//
#include <hip/hip_runtime.h>
#include <stdint.h>

#define NB 64
#define NC 512
#define NPTS 3000
#define MAXH 70
#define MAXW 40
#define HW (MAXH * MAXW)   // 2800
#define THREADS 256        // kernel A / fallback
#define THREADS_B 512      // gather kernel: 8 waves -> 2048 thr/CU (max occupancy)
#define CPB 32             // channels per block
#define NV4 750            // float4 per feature row (3000 floats)
#define NV4P 768           // padded buffer (float4) -> 12288 B
#define OV4 (HW / 4)       // 700 float4 per output row
#define FIXCAP 8192
// ws layout: [0..16) fix_cnt | [16..16+FIXCAP*4) fix_list | inv maps (64*2800 int)
#define WS_INV_OFF (16 + FIXCAP * 4)                 // 32784, 16B-aligned
#define WS_NEED    (WS_INV_OFF + NB * HW * 4)        // 749584 B

typedef float f32x4 __attribute__((ext_vector_type(4)));  // native vec for NT store

// async global -> LDS DMA, 16 B per lane (HW: wave-uniform base + lane*16)
__device__ __forceinline__ void gload_lds16(const void* g, void* l) {
    __builtin_amdgcn_global_load_lds(
        (const __attribute__((address_space(1))) uint32_t*)g,
        (__attribute__((address_space(3))) uint32_t*)l,
        16, 0, 0);
}

// reset the fixup counter (ws is NOT re-poisoned between replays)
__global__ void fm_zero_cnt(int* cnt) {
    if (threadIdx.x == 0) cnt[0] = 0;
}

// ============================================================================
// Kernel A: one block per batch item -- compute crop params + inverse map,
// write inv[b][HW] to workspace.
// ============================================================================
__launch_bounds__(THREADS)
__global__ void fm_inv_kernel(const int* __restrict__ ys,
                              const int* __restrict__ xs,
                              int* __restrict__ invg)
{
    __shared__ int inv[HW];        // 11.2 KB
    __shared__ int ybuf[NPTS];     // 12 KB
    __shared__ int xbuf[NPTS];     // 12 KB
    __shared__ int s_red[16];
    __shared__ int s_par[5];

    const int b   = blockIdx.x;
    const int tid = threadIdx.x;
    const int lane = tid & 63;
    const int w    = tid >> 6;

    const int* ysb = ys + b * NPTS;
    const int* xsb = xs + b * NPTS;

    int vminY = 0x7fffffff, vminX = 0x7fffffff;
    int vmaxY = -0x7fffffff, vmaxX = -0x7fffffff;
    for (int i = tid; i < NV4; i += THREADS) {
        int4 ya = ((const int4*)ysb)[i];
        int4 xa = ((const int4*)xsb)[i];
        ((int4*)ybuf)[i] = ya;
        ((int4*)xbuf)[i] = xa;
        int yv[4] = {ya.x, ya.y, ya.z, ya.w};
        int xv[4] = {xa.x, xa.y, xa.z, xa.w};
#pragma unroll
        for (int j = 0; j < 4; ++j) {
            if (yv[j] > -1) {
                vminY = min(vminY, yv[j]); vmaxY = max(vmaxY, yv[j]);
                vminX = min(vminX, xv[j]); vmaxX = max(vmaxX, xv[j]);
            }
        }
    }
    for (int i = tid; i < HW; i += THREADS) inv[i] = -1;
#pragma unroll
    for (int off = 32; off > 0; off >>= 1) {
        vminY = min(vminY, __shfl_xor(vminY, off));
        vmaxY = max(vmaxY, __shfl_xor(vmaxY, off));
        vminX = min(vminX, __shfl_xor(vminX, off));
        vmaxX = max(vmaxX, __shfl_xor(vmaxX, off));
    }
    if (lane == 0) {
        s_red[w]      = vminY;
        s_red[4  + w] = vmaxY;
        s_red[8  + w] = vminX;
        s_red[12 + w] = vmaxX;
    }
    __syncthreads();
    if (tid == 0) {
        int mnY = min(min(s_red[0], s_red[1]),   min(s_red[2],  s_red[3]));
        int mxY = max(max(s_red[4], s_red[5]),   max(s_red[6],  s_red[7]));
        int mnX = min(min(s_red[8], s_red[9]),   min(s_red[10], s_red[11]));
        int mxX = max(max(s_red[12], s_red[13]), max(s_red[14], s_red[15]));
        int h  = mxY - mnY + 1;
        int w_ = mxX - mnX + 1;
        int swap = (w_ > h) ? 1 : 0;
        int H0 = swap ? w_ : h;
        int W0 = swap ? h : w_;
        int h_dif = H0 - MAXH;
        int w_dif = W0 - MAXW;
        int cut_top  = (h_dif > 0) ? (h_dif + 1) / 2 : 0;
        int pad_top  = (h_dif > 0) ? 0 : (-h_dif + 1) / 2;
        int cut_left = (w_dif > 0) ? (w_dif + 1) / 2 : 0;
        int left_pad = (w_dif > 0) ? 0 : (-w_dif + 1) / 2;  // ref pads "right" on the LEFT
        s_par[0] = swap;
        s_par[1] = mnY;
        s_par[2] = mnX;
        s_par[3] = pad_top - cut_top;
        s_par[4] = left_pad - cut_left;
    }
    __syncthreads();
    {
        const int swp = s_par[0], mnY = s_par[1], mnX = s_par[2];
        const int roff = s_par[3], coff = s_par[4];
        for (int n = tid; n < NPTS; n += THREADS) {
            int y = ybuf[n];
            int x = xbuf[n];
            if (y > -1) {
                int r  = swp ? (x - mnX) : (y - mnY);
                int cl = swp ? (y - mnY) : (x - mnX);
                int rr = r + roff;
                int cc = cl + coff;
                if (rr >= 0 && rr < MAXH && cc >= 0 && cc < MAXW)
                    inv[rr * MAXW + cc] = n;   // unique targets per setup
            }
        }
    }
    __syncthreads();
    int4* dst = (int4*)(invg + b * HW);
    for (int i = tid; i < OV4; i += THREADS) dst[i] = ((const int4*)inv)[i];
}

// ============================================================================
// Kernel B: 512-thread (8-wave) gather with precomputed inv map.
// Triple-buffered LDS channel pipeline, 1 raw barrier + per-wave counted
// vmcnt per channel. 4 blocks/CU x 512 thr = 2048 thr/CU = max occupancy.
//
// Per-wave op counts (ragged split of 750 staging / 700 gather over 512 thr):
//   staging L: it0 all waves 1; it1 (i=512+tid<768) waves 0-3 -> L=2 w<4 else 1
//   stores  S: it0 all waves 1; it1 (i4=512+tid<700) waves 0-2 -> S=2 w<3 else 1
// Steady-state wait: retire loads(ci), keep stores(ci-1)+loads(ci+1):
//   N = S + L -> w<3:4, w==3:3, w>=4:2. Iter0: N = L(ch1) -> w<4:2 else 1.
// ============================================================================
__launch_bounds__(THREADS_B)
__global__ void fm_gather_pre_kernel(const float* __restrict__ feat,
                                     const int* __restrict__ invg,
                                     float* __restrict__ out,
                                     int* __restrict__ fix_cnt,
                                     int* __restrict__ fix_list,
                                     int fix_cap)
{
    __shared__ float4 tb[3][NV4P];          // 36.9 KB

    const int blocks_per_b = NC / CPB;      // 16
    const int b   = blockIdx.x / blocks_per_b;
    const int c0  = (blockIdx.x % blocks_per_b) * CPB;
    const int tid = threadIdx.x;
    const int w   = tid >> 6;               // wave id 0..7 (uniform per wave)

    // channel-invariant inv entries -> registers (2 coalesced int4 loads)
    int nreg[2][4];
    {
        const int4* src = (const int4*)(invg + b * HW);
#pragma unroll
        for (int it = 0; it < 2; ++it) {
            int i4 = it * THREADS_B + tid;
            if (i4 < OV4) {
                int4 t = src[i4];
                nreg[it][0] = t.x; nreg[it][1] = t.y;
                nreg[it][2] = t.z; nreg[it][3] = t.w;
            }
        }
    }

    // prologue: DMA ch0 into tb[0] (tail lanes clamp source; dest is pad)
    {
        const float4* src = (const float4*)(feat + (size_t)(b * NC + c0) * NPTS);
#pragma unroll
        for (int it = 0; it < 2; ++it) {
            int i = it * THREADS_B + tid;
            if (i < NV4P) {
                int s = (i < NV4) ? i : (NV4 - 1);
                gload_lds16(src + s, tb[0] + i);
            }
        }
    }

    int cur = 0;
    for (int ci = 0; ci < CPB; ++ci) {
        const int nxt = (cur == 2) ? 0 : cur + 1;
        if (ci + 1 < CPB) {   // async-prefetch next channel
            const float4* src =
                (const float4*)(feat + (size_t)(b * NC + c0 + ci + 1) * NPTS);
            float4* bn = tb[nxt];
#pragma unroll
            for (int it = 0; it < 2; ++it) {
                int i = it * THREADS_B + tid;
                if (i < NV4P) {
                    int s = (i < NV4) ? i : (NV4 - 1);
                    gload_lds16(src + s, bn + i);
                }
            }
        }
        // per-wave counted wait (w is wave-uniform -> no divergence cost)
        if (ci == 0) {
            if (w < 4) { asm volatile("s_waitcnt vmcnt(2)" ::: "memory"); }
            else       { asm volatile("s_waitcnt vmcnt(1)" ::: "memory"); }
        } else if (ci + 1 < CPB) {
            if (w < 3)       { asm volatile("s_waitcnt vmcnt(4)" ::: "memory"); }
            else if (w == 3) { asm volatile("s_waitcnt vmcnt(3)" ::: "memory"); }
            else             { asm volatile("s_waitcnt vmcnt(2)" ::: "memory"); }
        } else {
            asm volatile("s_waitcnt vmcnt(0)" ::: "memory");
        }
        __builtin_amdgcn_sched_barrier(0);
        __builtin_amdgcn_s_barrier();      // all waves' loads-ci landed
        __builtin_amdgcn_sched_barrier(0);

        const float* fp = (const float*)tb[cur];
        f32x4* orow = (f32x4*)(out + (size_t)(b * NC + c0 + ci) * HW);
#pragma unroll
        for (int it = 0; it < 2; ++it) {
            int i4 = it * THREADS_B + tid;
            if (i4 < OV4) {
                f32x4 v;
#pragma unroll
                for (int j = 0; j < 4; ++j) {
                    int n = nreg[it][j];
                    float val = 0.0f;
                    if (n >= 0) {
                        val = fp[n];
                        if (val == -1.0f) {
                            // scattered cell containing exact -1.0 -> zero whole cell
                            int pos = atomicAdd(fix_cnt, 1);
                            if (pos < fix_cap) fix_list[pos] = b * HW + i4 * 4 + j;
                        }
                    }
                    v[j] = val;
                }
                __builtin_nontemporal_store(v, &orow[i4]);
            }
        }
        cur = nxt;
    }
}

// ============================================================================
// Monolithic fallback (R8 kernel, used only if ws is too small for inv maps)
// ============================================================================
__launch_bounds__(THREADS)
__global__ void fm_gather_mono_kernel(const float* __restrict__ feat,
                                      const int* __restrict__ ys,
                                      const int* __restrict__ xs,
                                      float* __restrict__ out,
                                      int* __restrict__ fix_cnt,
                                      int* __restrict__ fix_list,
                                      int fix_cap)
{
    __shared__ float4 tb[3][NV4P];
    __shared__ int    s_red[16];
    __shared__ int    s_par[5];

    const int blocks_per_b = NC / CPB;
    const int b   = blockIdx.x / blocks_per_b;
    const int c0  = (blockIdx.x % blocks_per_b) * CPB;
    const int tid = threadIdx.x;
    const int lane = tid & 63;
    const int w    = tid >> 6;

    const int* ysb = ys + b * NPTS;
    const int* xsb = xs + b * NPTS;
    int* ybuf = (int*)tb[0];
    int* xbuf = (int*)tb[1];
    int* inv  = (int*)tb[2];

    int vminY = 0x7fffffff, vminX = 0x7fffffff;
    int vmaxY = -0x7fffffff, vmaxX = -0x7fffffff;
    for (int i = tid; i < NV4; i += THREADS) {
        int4 ya = ((const int4*)ysb)[i];
        int4 xa = ((const int4*)xsb)[i];
        ((int4*)ybuf)[i] = ya;
        ((int4*)xbuf)[i] = xa;
        int yv[4] = {ya.x, ya.y, ya.z, ya.w};
        int xv[4] = {xa.x, xa.y, xa.z, xa.w};
#pragma unroll
        for (int j = 0; j < 4; ++j) {
            if (yv[j] > -1) {
                vminY = min(vminY, yv[j]); vmaxY = max(vmaxY, yv[j]);
                vminX = min(vminX, xv[j]); vmaxX = max(vmaxX, xv[j]);
            }
        }
    }
    for (int i = tid; i < HW; i += THREADS) inv[i] = -1;
#pragma unroll
    for (int off = 32; off > 0; off >>= 1) {
        vminY = min(vminY, __shfl_xor(vminY, off));
        vmaxY = max(vmaxY, __shfl_xor(vmaxY, off));
        vminX = min(vminX, __shfl_xor(vminX, off));
        vmaxX = max(vmaxX, __shfl_xor(vmaxX, off));
    }
    if (lane == 0) {
        s_red[w]      = vminY;
        s_red[4  + w] = vmaxY;
        s_red[8  + w] = vminX;
        s_red[12 + w] = vmaxX;
    }
    __syncthreads();
    if (tid == 0) {
        int mnY = min(min(s_red[0], s_red[1]),   min(s_red[2],  s_red[3]));
        int mxY = max(max(s_red[4], s_red[5]),   max(s_red[6],  s_red[7]));
        int mnX = min(min(s_red[8], s_red[9]),   min(s_red[10], s_red[11]));
        int mxX = max(max(s_red[12], s_red[13]), max(s_red[14], s_red[15]));
        int h  = mxY - mnY + 1;
        int w_ = mxX - mnX + 1;
        int swap = (w_ > h) ? 1 : 0;
        int H0 = swap ? w_ : h;
        int W0 = swap ? h : w_;
        int h_dif = H0 - MAXH;
        int w_dif = W0 - MAXW;
        int cut_top  = (h_dif > 0) ? (h_dif + 1) / 2 : 0;
        int pad_top  = (h_dif > 0) ? 0 : (-h_dif + 1) / 2;
        int cut_left = (w_dif > 0) ? (w_dif + 1) / 2 : 0;
        int left_pad = (w_dif > 0) ? 0 : (-w_dif + 1) / 2;
        s_par[0] = swap;
        s_par[1] = mnY;
        s_par[2] = mnX;
        s_par[3] = pad_top - cut_top;
        s_par[4] = left_pad - cut_left;
    }
    __syncthreads();
    {
        const int swp = s_par[0], mnY = s_par[1], mnX = s_par[2];
        const int roff = s_par[3], coff = s_par[4];
        for (int n = tid; n < NPTS; n += THREADS) {
            int y = ybuf[n];
            int x = xbuf[n];
            if (y > -1) {
                int r  = swp ? (x - mnX) : (y - mnY);
                int cl = swp ? (y - mnY) : (x - mnX);
                int rr = r + roff;
                int cc = cl + coff;
                if (rr >= 0 && rr < MAXH && cc >= 0 && cc < MAXW)
                    inv[rr * MAXW + cc] = n;
            }
        }
    }
    __syncthreads();

    int nreg[3][4];
#pragma unroll
    for (int it = 0; it < 3; ++it) {
        int i4 = it * THREADS + tid;
        if (i4 < OV4) {
#pragma unroll
            for (int j = 0; j < 4; ++j) nreg[it][j] = inv[i4 * 4 + j];
        }
    }
    __syncthreads();

    {
        const float4* src = (const float4*)(feat + (size_t)(b * NC + c0) * NPTS);
#pragma unroll
        for (int it = 0; it < 3; ++it) {
            int i = it * THREADS + tid;
            int s = (i < NV4) ? i : (NV4 - 1);
            gload_lds16(src + s, tb[0] + i);
        }
    }

    int cur = 0;
    for (int ci = 0; ci < CPB; ++ci) {
        const int nxt = (cur == 2) ? 0 : cur + 1;
        if (ci + 1 < CPB) {
            const float4* src =
                (const float4*)(feat + (size_t)(b * NC + c0 + ci + 1) * NPTS);
            float4* bn = tb[nxt];
#pragma unroll
            for (int it = 0; it < 3; ++it) {
                int i = it * THREADS + tid;
                int s = (i < NV4) ? i : (NV4 - 1);
                gload_lds16(src + s, bn + i);
            }
        }
        if (ci == 0) {
            asm volatile("s_waitcnt vmcnt(3)" ::: "memory");
        } else if (ci + 1 < CPB) {
            asm volatile("s_waitcnt vmcnt(5)" ::: "memory");
        } else {
            asm volatile("s_waitcnt vmcnt(2)" ::: "memory");
        }
        __builtin_amdgcn_sched_barrier(0);
        __builtin_amdgcn_s_barrier();
        __builtin_amdgcn_sched_barrier(0);

        const float* fp = (const float*)tb[cur];
        f32x4* orow = (f32x4*)(out + (size_t)(b * NC + c0 + ci) * HW);
#pragma unroll
        for (int it = 0; it < 3; ++it) {
            int i4 = it * THREADS + tid;
            if (i4 < OV4) {
                f32x4 v;
#pragma unroll
                for (int j = 0; j < 4; ++j) {
                    int n = nreg[it][j];
                    float val = 0.0f;
                    if (n >= 0) {
                        val = fp[n];
                        if (val == -1.0f) {
                            int pos = atomicAdd(fix_cnt, 1);
                            if (pos < fix_cap) fix_list[pos] = b * HW + i4 * 4 + j;
                        }
                    }
                    v[j] = val;
                }
                __builtin_nontemporal_store(v, &orow[i4]);
            }
        }
        cur = nxt;
    }
}

__global__ void fm_fixup_kernel(const int* __restrict__ fix_cnt,
                                const int* __restrict__ fix_list,
                                int fix_cap,
                                float* __restrict__ out)
{
    int count = min(fix_cnt[0], fix_cap);
    long total = (long)count * NC;
    long stride = (long)gridDim.x * blockDim.x;
    for (long t = (long)blockIdx.x * blockDim.x + threadIdx.x; t < total; t += stride) {
        int e = (int)(t / NC);
        int c = (int)(t % NC);
        int cell = fix_list[e];
        int b   = cell / HW;
        int pos = cell % HW;
        __builtin_nontemporal_store(0.0f, &out[(size_t)(b * NC + c) * HW + pos]);
    }
}

extern "C" void kernel_launch(void* const* d_in, const int* in_sizes, int n_in,
                              void* d_out, int out_size, void* d_ws, size_t ws_size,
                              hipStream_t stream) {
    const float* feat = (const float*)d_in[0];
    const int*   ys   = (const int*)d_in[1];
    const int*   xs   = (const int*)d_in[2];
    float* out = (float*)d_out;

    int* fix_cnt  = (int*)d_ws;
    int* fix_list = (int*)((char*)d_ws + 16);

    fm_zero_cnt<<<1, 64, 0, stream>>>(fix_cnt);

    const int grid = NB * (NC / CPB);  // 1024 blocks

    if (ws_size >= (size_t)WS_NEED) {
        int* invg = (int*)((char*)d_ws + WS_INV_OFF);
        fm_inv_kernel<<<NB, THREADS, 0, stream>>>(ys, xs, invg);
        fm_gather_pre_kernel<<<grid, THREADS_B, 0, stream>>>(feat, invg, out,
                                                             fix_cnt, fix_list,
                                                             FIXCAP);
        fm_fixup_kernel<<<128, 256, 0, stream>>>(fix_cnt, fix_list, FIXCAP, out);
    } else {
        int fix_cap = 0;
        if (ws_size > 16) {
            size_t avail = (ws_size - 16) / 4;
            fix_cap = (int)((avail < FIXCAP) ? avail : FIXCAP);
        }
        fm_gather_mono_kernel<<<grid, THREADS, 0, stream>>>(feat, ys, xs, out,
                                                            fix_cnt, fix_list,
                                                            fix_cap);
        fm_fixup_kernel<<<128, 256, 0, stream>>>(fix_cnt, fix_list, fix_cap, out);
    }
}